// Round 9
// baseline (196.247 us; speedup 1.0000x reference)
//
#include <hip/hip_runtime.h>

typedef __attribute__((ext_vector_type(8))) __bf16 bf16x8;
typedef __attribute__((ext_vector_type(4))) __bf16 bf16x4;
typedef __attribute__((ext_vector_type(4))) float f32x4;

typedef __attribute__((address_space(1))) void as1_void;
typedef __attribute__((address_space(3))) void as3_void;

__device__ __forceinline__ void gl_lds16(const void* g, void* l) {
    __builtin_amdgcn_global_load_lds((const as1_void*)g, (as3_void*)l, 16, 0, 0);
}

// swizzled fragment pointer for a [rows][64] bf16 LDS buffer (row = 128 B,
// 16-byte chunks XOR-swizzled by row&7 to kill bank conflicts)
__device__ __forceinline__ const bf16x8* swz(const __bf16* base, int row, int chunk) {
    return (const bf16x8*)((const char*)base + row * 128 + ((chunk ^ (row & 7)) * 16));
}

#define QSCALE (0.125f * 1.44269504f)   // 1/sqrt(64) * log2(e), applied at q-GEMM

// ---------------------------------------------------------------------------
// prep: pure-BW conversions only (no GEMM, no reduction tails).
//   [0,1024)    WvT transpose tiles    wvt[n][k] = caw[k][2048+n]
//   [1024,2048) WpT transpose tiles    wpt[n][k] = cpw[k][n]
//   [2048,3072) WqT transpose tiles    wqt[n][k] = caw[k][n]
//   [3072,4096) WkN convert            wkn[n][k] = caw[n][1024+k]
//   [4096,8192) x convert
// ---------------------------------------------------------------------------
__global__ __launch_bounds__(256) void prep_kernel(
    const float* __restrict__ x, const float* __restrict__ caw,
    const float* __restrict__ cpw,
    __bf16* __restrict__ xb, __bf16* __restrict__ wvt,
    __bf16* __restrict__ wpt, __bf16* __restrict__ wqt,
    __bf16* __restrict__ wkn)
{
    __shared__ float tile[32 * 33];
    int bid = blockIdx.x;
    int tid = threadIdx.x;
    if (bid < 1024) {                      // WvT[n][k] = caw[k][2048+n]
        int nt = bid >> 5, kt = bid & 31;
        int tx = tid & 31, ty = tid >> 5;  // 32 x 8
        int n0 = nt * 32, k0 = kt * 32;
#pragma unroll
        for (int i = 0; i < 4; ++i)
            tile[(ty + i * 8) * 33 + tx] = caw[(long)(k0 + ty + i * 8) * 3072 + 2048 + n0 + tx];
        __syncthreads();
#pragma unroll
        for (int i = 0; i < 4; ++i)
            wvt[(long)(n0 + ty + i * 8) * 1024 + k0 + tx] = (__bf16)tile[tx * 33 + ty + i * 8];
    } else if (bid < 2048) {               // WpT[n][k] = cpw[k][n]
        int v = bid - 1024;
        int nt = v >> 5, kt = v & 31;
        int tx = tid & 31, ty = tid >> 5;
        int n0 = nt * 32, k0 = kt * 32;
#pragma unroll
        for (int i = 0; i < 4; ++i)
            tile[(ty + i * 8) * 33 + tx] = cpw[(long)(k0 + ty + i * 8) * 1024 + n0 + tx];
        __syncthreads();
#pragma unroll
        for (int i = 0; i < 4; ++i)
            wpt[(long)(n0 + ty + i * 8) * 1024 + k0 + tx] = (__bf16)tile[tx * 33 + ty + i * 8];
    } else if (bid < 3072) {               // WqT[n][k] = caw[k][n]
        int v = bid - 2048;
        int nt = v >> 5, kt = v & 31;
        int tx = tid & 31, ty = tid >> 5;
        int n0 = nt * 32, k0 = kt * 32;
#pragma unroll
        for (int i = 0; i < 4; ++i)
            tile[(ty + i * 8) * 33 + tx] = caw[(long)(k0 + ty + i * 8) * 3072 + n0 + tx];
        __syncthreads();
#pragma unroll
        for (int i = 0; i < 4; ++i)
            wqt[(long)(n0 + ty + i * 8) * 1024 + k0 + tx] = (__bf16)tile[tx * 33 + ty + i * 8];
    } else if (bid < 4096) {               // WkN[n][k] = caw[n][1024+k]
        int e = (bid - 3072) * 1024 + tid * 4;
        int n = e >> 10, k = e & 1023;
        float4 f = *(const float4*)(caw + (long)n * 3072 + 1024 + k);
        bf16x4 o = {(__bf16)f.x, (__bf16)f.y, (__bf16)f.z, (__bf16)f.w};
        *(bf16x4*)(wkn + e) = o;
    } else {                               // x convert
        long e = (long)(bid - 4096) * 1024 + tid * 4;
        float4 f = *(const float4*)(x + e);
        bf16x4 o = {(__bf16)f.x, (__bf16)f.y, (__bf16)f.z, (__bf16)f.w};
        *(bf16x4*)(xb + e) = o;
    }
}

// ---------------------------------------------------------------------------
// Generic GEMM: C[M,*] = (A[M,K] x BT[N,K] + bias) * oscale.  BK = 64,
// XOR-chunk-swizzled LDS (128 B rows). NT = BN/32 16-col groups per wave.
// ---------------------------------------------------------------------------
template <bool BF16OUT, int BN>
__global__ __launch_bounds__(256) void gemm_bt(
    const __bf16* __restrict__ A, int lda,
    const __bf16* __restrict__ B, int ldb,
    const float* __restrict__ bias,
    void* __restrict__ C, int ldc, int K, float oscale)
{
    constexpr int NT = BN / 32;            // 16-col groups per wave
    __shared__ __bf16 As[128 * 64];
    __shared__ __bf16 Bs[BN * 64];
    const int tid = threadIdx.x;
    const int lane = tid & 63;
    const int wave = tid >> 6;
    const int quad = lane >> 4, l16 = lane & 15;
    const long m0 = (long)blockIdx.y * 128;
    const long n0 = (long)blockIdx.x * BN;
    const int wm = (wave >> 1) * 64, wn = (wave & 1) * (BN / 2);

    f32x4 acc[4][NT] = {};

    for (int k0 = 0; k0 < K; k0 += 64) {
#pragma unroll
        for (int c = tid; c < (128 + BN) * 8; c += 256) {
            int row = c >> 3, cc = (c & 7) ^ (row & 7);
            if (row < 128)
                gl_lds16(A + (m0 + row) * lda + k0 + cc * 8, As + c * 8);
            else
                gl_lds16(B + (n0 + row - 128) * ldb + k0 + cc * 8, Bs + (c - 1024) * 8);
        }
        __syncthreads();
#pragma unroll
        for (int kk = 0; kk < 2; ++kk) {
            bf16x8 af[4], bfr[NT];
#pragma unroll
            for (int i = 0; i < 4; ++i)
                af[i] = *swz(As, wm + i * 16 + l16, kk * 4 + quad);
#pragma unroll
            for (int j = 0; j < NT; ++j)
                bfr[j] = *swz(Bs, wn + j * 16 + l16, kk * 4 + quad);
#pragma unroll
            for (int i = 0; i < 4; ++i)
#pragma unroll
                for (int j = 0; j < NT; ++j)
                    acc[i][j] = __builtin_amdgcn_mfma_f32_16x16x32_bf16(af[i], bfr[j], acc[i][j], 0, 0, 0);
        }
        __syncthreads();
    }
#pragma unroll
    for (int i = 0; i < 4; ++i) {
        long row = m0 + wm + i * 16 + quad * 4;
#pragma unroll
        for (int j = 0; j < NT; ++j) {
            int col = (int)n0 + wn + j * 16 + l16;
            float bb = bias ? bias[col] : 0.f;
#pragma unroll
            for (int r = 0; r < 4; ++r) {
                float v = (acc[i][j][r] + bb) * oscale;
                if (BF16OUT)
                    ((__bf16*)C)[(row + r) * ldc + col] = (__bf16)v;
                else
                    ((float*)C)[(row + r) * ldc + col] = v;
            }
        }
    }
}

// ---------------------------------------------------------------------------
// gemm_qv: grid (16, 32). B = [WkN ; Wv^T] (2048 rows, contiguous). BK=64.
// blockIdx.x < 8  : q-half  A=tb : q = (t Wk^T + kb)*QSCALE -> Qout row-major
// blockIdx.x >= 8 : v-half  A=xb : v = x Wv + vb -> VTout via in-LDS transpose
// bias base = cab+1024 so col-indexing hits kb for q-half, vb for v-half.
// ---------------------------------------------------------------------------
__global__ __launch_bounds__(256) void gemm_qv(
    const __bf16* __restrict__ Aq,      // tb [4096][1024]
    const __bf16* __restrict__ Av,      // xb [4096][1024]
    const __bf16* __restrict__ B,       // [2048][1024] = [wkn ; wvt]
    const float* __restrict__ bias,     // cab + 1024
    __bf16* __restrict__ Qout,          // [4096][1024]
    __bf16* __restrict__ VTout)         // [2048][2048]
{
    __shared__ __bf16 smem[128 * 136];  // main loop uses first 16384 elems
    __bf16* As = smem;
    __bf16* Bs = smem + 8192;
    const int tid = threadIdx.x;
    const int lane = tid & 63;
    const int wave = tid >> 6;
    const int quad = lane >> 4, l16 = lane & 15;
    const long m0 = (long)blockIdx.y * 128;
    const long n0 = (long)blockIdx.x * 128;
    const int wm = (wave >> 1) * 64, wn = (wave & 1) * 64;
    const __bf16* A = (n0 < 1024) ? Aq : Av;

    f32x4 acc[4][4] = {};

    for (int k0 = 0; k0 < 1024; k0 += 64) {
#pragma unroll
        for (int c = tid; c < 2048; c += 256) {
            int row = c >> 3, cc = (c & 7) ^ (row & 7);
            if (row < 128)
                gl_lds16(A + (m0 + row) * 1024 + k0 + cc * 8, As + c * 8);
            else
                gl_lds16(B + (n0 + row - 128) * 1024 + k0 + cc * 8, Bs + (c - 1024) * 8);
        }
        __syncthreads();
#pragma unroll
        for (int kk = 0; kk < 2; ++kk) {
            bf16x8 af[4], bfr[4];
#pragma unroll
            for (int i = 0; i < 4; ++i)
                af[i] = *swz(As, wm + i * 16 + l16, kk * 4 + quad);
#pragma unroll
            for (int j = 0; j < 4; ++j)
                bfr[j] = *swz(Bs, wn + j * 16 + l16, kk * 4 + quad);
#pragma unroll
            for (int i = 0; i < 4; ++i)
#pragma unroll
                for (int j = 0; j < 4; ++j)
                    acc[i][j] = __builtin_amdgcn_mfma_f32_16x16x32_bf16(af[i], bfr[j], acc[i][j], 0, 0, 0);
        }
        __syncthreads();
    }

    if (n0 < 1024) {
        // q-half: normal row-major store, scaled
#pragma unroll
        for (int i = 0; i < 4; ++i) {
            long row = m0 + wm + i * 16 + quad * 4;
#pragma unroll
            for (int j = 0; j < 4; ++j) {
                int col = (int)n0 + wn + j * 16 + l16;
                float bb = bias[col];
#pragma unroll
                for (int r = 0; r < 4; ++r)
                    Qout[(row + r) * 1024 + col] = (__bf16)((acc[i][j][r] + bb) * QSCALE);
            }
        }
    } else {
        // v-half: transpose through LDS (pitch 136), coalesced V^T rows out.
        __syncthreads();
#pragma unroll
        for (int i = 0; i < 4; ++i) {
#pragma unroll
            for (int j = 0; j < 4; ++j) {
                int col = (int)n0 + wn + j * 16 + l16;
                float bb = bias[col];
                bf16x4 v;
#pragma unroll
                for (int r = 0; r < 4; ++r) v[r] = (__bf16)(acc[i][j][r] + bb);
                *(bf16x4*)(smem + (wn + j * 16 + l16) * 136 + wm + i * 16 + quad * 4) = v;
            }
        }
        __syncthreads();
        const int d0 = (int)n0 - 1024;
        const int bb = (int)(m0 >> 11);
        const int sl = (int)(m0 & 2047);
#pragma unroll
        for (int pass = 0; pass < 16; ++pass) {
            int idx = pass * 256 + tid;
            int n = idx >> 5;             // 0..127
            int mc = (idx & 31) * 4;      // 0..124
            bf16x4 v = *(const bf16x4*)(smem + n * 136 + mc);
            *(bf16x4*)(VTout + ((long)(bb * 1024 + d0 + n)) * 2048 + sl + mc) = v;
        }
    }
}

// ---------------------------------------------------------------------------
// Flash attention, no-max softmax, pair-balanced + COOPERATIVE SPLIT.
// grid (32, 16) x 512 threads: x = bh, y = pair (qa, qb=31-qa).
// j <= qa : full mode — waves 0-3 run tile qa, waves 4-7 run tile qb.
// j >  qa : split mode — all 8 waves run tile qb; pair (s, s+4) splits
//   strip s: g0 takes kv 0..31 (kt 0,1) + PV kk=0; g1 takes kv 32..63 + kk=1.
//   P-chunk XOR layout keeps the two waves' LDS bytes disjoint (bit2 of
//   chunk^m differs), so no cross-wave P dependency; g0 partials merged via
//   LDS at the end. Critical path = 18(qa+1)+9(qb-qa) = 297 for EVERY block.
// ---------------------------------------------------------------------------
__global__ __launch_bounds__(512) void attn_kernel(
    const __bf16* __restrict__ Q,   // [4096][1024], pre-scaled
    const __bf16* __restrict__ Xb,  // [4096][1024]
    const __bf16* __restrict__ VT,  // [2048][2048]
    __bf16* __restrict__ O)         // [4096][1024]
{
    __shared__ __bf16 Ks[2 * 8192];
    __shared__ __bf16 Vs[2 * 8192];
    __shared__ __bf16 Ps[8 * 1024];
    const int tid = threadIdx.x;
    const int lane = tid & 63;
    const int wave = tid >> 6;        // 0..7
    const int group = wave >> 2;      // 0 -> qa (helper), 1 -> qb
    const int w4 = wave & 3;
    const int quad = lane >> 4, l16 = lane & 15;
    const int qa = blockIdx.y;        // 0..15
    const int qb = 31 - qa;           // 16..31
    const int qt = group ? qb : qa;
    const int bh = blockIdx.x;
    const int b = bh >> 4, h = bh & 15;
    const long rowbase = (long)b * 2048;

    const int s0 = tid;               // 0..511, row = s0>>3 in [0,64)
    const int c0 = ((s0 & 7) ^ ((s0 >> 3) & 7)) * 8;

    bf16x8 ones;
#pragma unroll
    for (int i = 0; i < 8; ++i) ones[i] = (__bf16)1.0f;

    // Q strips for BOTH tiles (g0 needs qa for full mode + qb for split mode)
    bf16x8 qfa[2], qfb[2];
    {
        const __bf16* qpa = Q + (rowbase + qa * 64 + w4 * 16 + l16) * 1024 + h * 64 + quad * 8;
        const __bf16* qpb = Q + (rowbase + qb * 64 + w4 * 16 + l16) * 1024 + h * 64 + quad * 8;
        qfa[0] = *(const bf16x8*)(qpa);
        qfa[1] = *(const bf16x8*)(qpa + 32);
        qfb[0] = *(const bf16x8*)(qpb);
        qfb[1] = *(const bf16x8*)(qpb + 32);
    }

    const __bf16* kp0 = Xb + (rowbase + (s0 >> 3)) * 1024 + h * 64 + c0;
    const __bf16* vp0 = VT + ((long)(b * 1024 + h * 64 + (s0 >> 3))) * 2048 + c0;

    auto stage_tile = [&](int j, int buf, int sub) {
        gl_lds16(kp0 + (long)j * 65536, Ks + buf * 8192 + sub * 4096 + s0 * 8);
        gl_lds16(vp0 + j * 64, Vs + buf * 8192 + sub * 4096 + s0 * 8);
    };
    stage_tile(0, 0, 0);
    stage_tile(1, 0, 1);

    const int nouter = (qb + 2) >> 1;     // ceil((qb+1)/2)

    f32x4 oacc[4] = {};       // own tile output (g0: qa, g1: qb)
    f32x4 oacch[4] = {};      // g0 only: qb-tile kk=0 partials
    f32x4 lacc = {}, lacch = {};
    __bf16* Pown = Ps + wave * 1024;  // full-mode per-wave buffer
    __bf16* Pspl = Ps + w4 * 1024;    // split-mode pair-shared buffer

    for (int jj = 0; jj < nouter; ++jj) {
        __syncthreads();                  // buf[jj&1] ready; prev reads done
        if (jj + 1 < nouter) {
            stage_tile(2 * jj + 2, (jj + 1) & 1, 0);
            stage_tile(2 * jj + 3, (jj + 1) & 1, 1);
        }

#pragma unroll
        for (int sub = 0; sub < 2; ++sub) {
            const int j = 2 * jj + sub;
            // full->split transition inside an epoch (qa even): fence the
            // WAR on g0's P buffer (g0 read chunks 4-7 at j==qa; g1 writes
            // them at j==qa+1).
            if (sub == 1 && 2 * jj == qa) __syncthreads();
            if (j > qb) continue;         // wave-uniform
            const __bf16* Kb = Ks + (jj & 1) * 8192 + sub * 4096;
            const __bf16* Vb = Vs + (jj & 1) * 8192 + sub * 4096;

            if (j <= qa) {
                // ---- FULL mode: each group on its own tile ----
                bf16x8 kf[2][4], vf[2][4];
#pragma unroll
                for (int kk = 0; kk < 2; ++kk)
#pragma unroll
                    for (int kt = 0; kt < 4; ++kt) {
                        kf[kk][kt] = *swz(Kb, kt * 16 + l16, kk * 4 + quad);
                        vf[kk][kt] = *swz(Vb, kt * 16 + l16, kk * 4 + quad);
                    }

                f32x4 sacc[4] = {};
                __builtin_amdgcn_s_setprio(1);
#pragma unroll
                for (int kk = 0; kk < 2; ++kk) {
                    bf16x8 qf = group ? qfb[kk] : qfa[kk];
#pragma unroll
                    for (int kt = 0; kt < 4; ++kt)
                        sacc[kt] = __builtin_amdgcn_mfma_f32_16x16x32_bf16(
                            kf[kk][kt], qf, sacc[kt], 0, 0, 0);
                }
                __builtin_amdgcn_s_setprio(0);

                if (j == qt) {            // diagonal only possible for g0
                    const int qloc = w4 * 16 + l16;
#pragma unroll
                    for (int kt = 0; kt < 4; ++kt) {
                        bf16x4 pk;
#pragma unroll
                        for (int r = 0; r < 4; ++r) {
                            float s = sacc[kt][r];
                            if (kt * 16 + quad * 4 + r > qloc) s = -1e30f;
                            pk[r] = (__bf16)exp2f(s);
                        }
                        *(bf16x4*)((char*)Pown + l16 * 128 +
                                   (((kt * 2 + (quad >> 1)) ^ (l16 & 7)) * 16) + (quad & 1) * 8) = pk;
                    }
                } else {
#pragma unroll
                    for (int kt = 0; kt < 4; ++kt) {
                        bf16x4 pk;
#pragma unroll
                        for (int r = 0; r < 4; ++r)
                            pk[r] = (__bf16)exp2f(sacc[kt][r]);
                        *(bf16x4*)((char*)Pown + l16 * 128 +
                                   (((kt * 2 + (quad >> 1)) ^ (l16 & 7)) * 16) + (quad & 1) * 8) = pk;
                    }
                }

                __builtin_amdgcn_s_setprio(1);
#pragma unroll
                for (int kk = 0; kk < 2; ++kk) {
                    bf16x8 pf = *swz(Pown, l16, kk * 4 + quad);
                    lacc = __builtin_amdgcn_mfma_f32_16x16x32_bf16(ones, pf, lacc, 0, 0, 0);
#pragma unroll
                    for (int dt = 0; dt < 4; ++dt)
                        oacc[dt] = __builtin_amdgcn_mfma_f32_16x16x32_bf16(
                            vf[kk][dt], pf, oacc[dt], 0, 0, 0);
                }
                __builtin_amdgcn_s_setprio(0);
            } else {
                // ---- SPLIT mode: pair (s, s+4) shares strip s of tile qb ----
                const int ktb = group * 2;     // kv half: 0..31 or 32..63
                bf16x8 kf2[2][2], vf2[4];
#pragma unroll
                for (int kk = 0; kk < 2; ++kk)
#pragma unroll
                    for (int t = 0; t < 2; ++t)
                        kf2[kk][t] = *swz(Kb, (ktb + t) * 16 + l16, kk * 4 + quad);
#pragma unroll
                for (int dt = 0; dt < 4; ++dt)
                    vf2[dt] = *swz(Vb, dt * 16 + l16, group * 4 + quad);

                f32x4 s2[2] = {};
                __builtin_amdgcn_s_setprio(1);
#pragma unroll
                for (int kk = 0; kk < 2; ++kk)
#pragma unroll
                    for (int t = 0; t < 2; ++t)
                        s2[t] = __builtin_amdgcn_mfma_f32_16x16x32_bf16(
                            kf2[kk][t], qfb[kk], s2[t], 0, 0, 0);
                __builtin_amdgcn_s_setprio(0);

                const int qloc = w4 * 16 + l16;
                const bool diag = (j == qb);
#pragma unroll
                for (int t = 0; t < 2; ++t) {
                    const int kt = ktb + t;
                    bf16x4 pk;
#pragma unroll
                    for (int r = 0; r < 4; ++r) {
                        float s = s2[t][r];
                        if (diag && kt * 16 + quad * 4 + r > qloc) s = -1e30f;
                        pk[r] = (__bf16)exp2f(s);
                    }
                    *(bf16x4*)((char*)Pspl + l16 * 128 +
                               (((kt * 2 + (quad >> 1)) ^ (l16 & 7)) * 16) + (quad & 1) * 8) = pk;
                }

                __builtin_amdgcn_s_setprio(1);
                bf16x8 pf = *swz(Pspl, l16, group * 4 + quad);
                if (group) {
                    lacc = __builtin_amdgcn_mfma_f32_16x16x32_bf16(ones, pf, lacc, 0, 0, 0);
#pragma unroll
                    for (int dt = 0; dt < 4; ++dt)
                        oacc[dt] = __builtin_amdgcn_mfma_f32_16x16x32_bf16(
                            vf2[dt], pf, oacc[dt], 0, 0, 0);
                } else {
                    lacch = __builtin_amdgcn_mfma_f32_16x16x32_bf16(ones, pf, lacch, 0, 0, 0);
#pragma unroll
                    for (int dt = 0; dt < 4; ++dt)
                        oacch[dt] = __builtin_amdgcn_mfma_f32_16x16x32_bf16(
                            vf2[dt], pf, oacch[dt], 0, 0, 0);
                }
                __builtin_amdgcn_s_setprio(0);
            }
        }
    }

    // merge g0's qb-tile partials into g1, then epilogue
    __syncthreads();
    float* xch = (float*)Ks;              // staging region no longer needed
    if (!group) {
        const int base = (w4 * 64 + lane) * 20;   // 80 B stride, 16B-aligned
#pragma unroll
        for (int dt = 0; dt < 4; ++dt)
            *(f32x4*)(xch + base + dt * 4) = oacch[dt];
        xch[base + 16] = lacch[0];
    }
    __syncthreads();
    if (group) {
        const int base = (w4 * 64 + lane) * 20;
#pragma unroll
        for (int dt = 0; dt < 4; ++dt) {
            f32x4 part = *(const f32x4*)(xch + base + dt * 4);
#pragma unroll
            for (int r = 0; r < 4; ++r) oacc[dt][r] += part[r];
        }
        lacc[0] += xch[base + 16];
    }
    {
        float inv = 1.0f / lacc[0];
        long row = rowbase + qt * 64 + w4 * 16 + l16;
#pragma unroll
        for (int dt = 0; dt < 4; ++dt) {
            bf16x4 ov;
#pragma unroll
            for (int r = 0; r < 4; ++r) ov[r] = (__bf16)(oacc[dt][r] * inv);
            *(bf16x4*)(O + row * 1024 + h * 64 + dt * 16 + quad * 4) = ov;
        }
    }
}

// ---------------------------------------------------------------------------
extern "C" void kernel_launch(void* const* d_in, const int* in_sizes, int n_in,
                              void* d_out, int out_size, void* d_ws, size_t ws_size,
                              hipStream_t stream) {
    const float* x   = (const float*)d_in[0];
    const float* caw = (const float*)d_in[1];
    const float* cab = (const float*)d_in[2];
    const float* cpw = (const float*)d_in[3];
    const float* cpb = (const float*)d_in[4];

    char* p = (char*)d_ws;
    auto alloc = [&](size_t bytes) {
        void* r = (void*)p;
        p += (bytes + 255) & ~(size_t)255;
        return r;
    };
    __bf16* xb    = (__bf16*)alloc(4096UL * 1024 * 2);   // x bf16
    __bf16* wkn   = (__bf16*)alloc(1024UL * 1024 * 2);   // Wk rows
    __bf16* wvt   = (__bf16*)alloc(1024UL * 1024 * 2);   // Wv^T (contiguous after wkn!)
    __bf16* wqt   = (__bf16*)alloc(1024UL * 1024 * 2);   // Wq^T
    __bf16* wpt   = (__bf16*)alloc(1024UL * 1024 * 2);   // Wp^T
    __bf16* tb    = (__bf16*)alloc(4096UL * 1024 * 2);   // t = x Wq + qb; reused as attn out
    __bf16* qbuf  = (__bf16*)alloc(4096UL * 1024 * 2);   // q (pre-scaled)
    __bf16* vt    = (__bf16*)alloc(2048UL * 2048 * 2);   // V^T per (b,h)

    // pure-BW prep: converts + transposes, no serial tails
    prep_kernel<<<8192, 256, 0, stream>>>(x, caw, cpw, xb, wvt, wpt, wqt, wkn);
    // t = x Wq + qb (bf16)
    gemm_bt<true, 64><<<dim3(16, 32), 256, 0, stream>>>(xb, 1024, wqt, 1024, cab,
                                                        (void*)tb, 1024, 1024, 1.0f);
    // q = (t Wk^T + kb)*QSCALE -> qbuf ; V^T -> vt (fused, single launch)
    gemm_qv<<<dim3(16, 32), 256, 0, stream>>>(tb, xb, wkn, cab + 1024, qbuf, vt);
    // attention (pair-balanced + cooperative split: constant 297-unit path)
    attn_kernel<<<dim3(32, 16), 512, 0, stream>>>(qbuf, xb, vt, tb);
    // out = attn @ Wp + pb (fp32)
    gemm_bt<false, 64><<<dim3(16, 32), 256, 0, stream>>>(tb, 1024, wpt, 1024, cpb,
                                                         d_out, 1024, 1024, 1.0f);
    (void)in_sizes; (void)n_in; (void)out_size; (void)ws_size;
}

// Round 10
// 174.861 us; speedup vs baseline: 1.1223x; 1.1223x over previous
//
#include <hip/hip_runtime.h>

typedef __attribute__((ext_vector_type(8))) __bf16 bf16x8;
typedef __attribute__((ext_vector_type(4))) __bf16 bf16x4;
typedef __attribute__((ext_vector_type(4))) float f32x4;

typedef __attribute__((address_space(1))) void as1_void;
typedef __attribute__((address_space(3))) void as3_void;

__device__ __forceinline__ void gl_lds16(const void* g, void* l) {
    __builtin_amdgcn_global_load_lds((const as1_void*)g, (as3_void*)l, 16, 0, 0);
}

// swizzled fragment pointer for a [rows][64] bf16 LDS buffer (row = 128 B,
// 16-byte chunks XOR-swizzled by row&7 to kill bank conflicts)
__device__ __forceinline__ const bf16x8* swz(const __bf16* base, int row, int chunk) {
    return (const bf16x8*)((const char*)base + row * 128 + ((chunk ^ (row & 7)) * 16));
}

#define QSCALE (0.125f * 1.44269504f)   // 1/sqrt(64) * log2(e), applied at q

// ---------------------------------------------------------------------------
// prep: pure-BW conversions only (no GEMM, no reduction tails).
//   [0,1024)    WvT transpose tiles    wvt[n][k] = caw[k][2048+n]
//   [1024,2048) WpT transpose tiles    wpt[n][k] = cpw[k][n]
//   [2048,3072) WqT transpose tiles    wqt[n][k] = caw[k][n]
//   [3072,4096) WkN convert            wkn[n][k] = caw[n][1024+k]
//   [4096,8192) x convert
// ---------------------------------------------------------------------------
__global__ __launch_bounds__(256) void prep_kernel(
    const float* __restrict__ x, const float* __restrict__ caw,
    const float* __restrict__ cpw,
    __bf16* __restrict__ xb, __bf16* __restrict__ wvt,
    __bf16* __restrict__ wpt, __bf16* __restrict__ wqt,
    __bf16* __restrict__ wkn)
{
    __shared__ float tile[32 * 33];
    int bid = blockIdx.x;
    int tid = threadIdx.x;
    if (bid < 1024) {                      // WvT[n][k] = caw[k][2048+n]
        int nt = bid >> 5, kt = bid & 31;
        int tx = tid & 31, ty = tid >> 5;  // 32 x 8
        int n0 = nt * 32, k0 = kt * 32;
#pragma unroll
        for (int i = 0; i < 4; ++i)
            tile[(ty + i * 8) * 33 + tx] = caw[(long)(k0 + ty + i * 8) * 3072 + 2048 + n0 + tx];
        __syncthreads();
#pragma unroll
        for (int i = 0; i < 4; ++i)
            wvt[(long)(n0 + ty + i * 8) * 1024 + k0 + tx] = (__bf16)tile[tx * 33 + ty + i * 8];
    } else if (bid < 2048) {               // WpT[n][k] = cpw[k][n]
        int v = bid - 1024;
        int nt = v >> 5, kt = v & 31;
        int tx = tid & 31, ty = tid >> 5;
        int n0 = nt * 32, k0 = kt * 32;
#pragma unroll
        for (int i = 0; i < 4; ++i)
            tile[(ty + i * 8) * 33 + tx] = cpw[(long)(k0 + ty + i * 8) * 1024 + n0 + tx];
        __syncthreads();
#pragma unroll
        for (int i = 0; i < 4; ++i)
            wpt[(long)(n0 + ty + i * 8) * 1024 + k0 + tx] = (__bf16)tile[tx * 33 + ty + i * 8];
    } else if (bid < 3072) {               // WqT[n][k] = caw[k][n]
        int v = bid - 2048;
        int nt = v >> 5, kt = v & 31;
        int tx = tid & 31, ty = tid >> 5;
        int n0 = nt * 32, k0 = kt * 32;
#pragma unroll
        for (int i = 0; i < 4; ++i)
            tile[(ty + i * 8) * 33 + tx] = caw[(long)(k0 + ty + i * 8) * 3072 + n0 + tx];
        __syncthreads();
#pragma unroll
        for (int i = 0; i < 4; ++i)
            wqt[(long)(n0 + ty + i * 8) * 1024 + k0 + tx] = (__bf16)tile[tx * 33 + ty + i * 8];
    } else if (bid < 4096) {               // WkN[n][k] = caw[n][1024+k]
        int e = (bid - 3072) * 1024 + tid * 4;
        int n = e >> 10, k = e & 1023;
        float4 f = *(const float4*)(caw + (long)n * 3072 + 1024 + k);
        bf16x4 o = {(__bf16)f.x, (__bf16)f.y, (__bf16)f.z, (__bf16)f.w};
        *(bf16x4*)(wkn + e) = o;
    } else {                               // x convert
        long e = (long)(bid - 4096) * 1024 + tid * 4;
        float4 f = *(const float4*)(x + e);
        bf16x4 o = {(__bf16)f.x, (__bf16)f.y, (__bf16)f.z, (__bf16)f.w};
        *(bf16x4*)(xb + e) = o;
    }
}

// ---------------------------------------------------------------------------
// gemm_tv: 768 blocks (3/CU), one launch for the two independent GEMMs:
//   bid < 512 : t-tile  (128x64)  t  = x Wq + qb        -> tb bf16 row-major
//   bid >= 512: v-tile  (128x128) v  = x Wv + vb        -> vt via LDS transpose
// ---------------------------------------------------------------------------
__global__ __launch_bounds__(256) void gemm_tv(
    const __bf16* __restrict__ xb, const __bf16* __restrict__ wqt,
    const __bf16* __restrict__ wvt, const float* __restrict__ cab,
    __bf16* __restrict__ tb, __bf16* __restrict__ vt)
{
    __shared__ __bf16 smem[128 * 136];
    const int bid = blockIdx.x;
    const int tid = threadIdx.x;
    const int lane = tid & 63;
    const int wave = tid >> 6;
    const int quad = lane >> 4, l16 = lane & 15;

    if (bid < 512) {
        // ---- t-tile: BN=64 ----
        __bf16* As = smem;               // 128 x 64
        __bf16* Bs = smem + 8192;        // 64 x 64
        const int bx = bid & 15, by = bid >> 4;
        const long m0 = (long)by * 128;
        const long n0 = (long)bx * 64;
        const int wm = (wave >> 1) * 64, wn = (wave & 1) * 32;

        f32x4 acc[4][2] = {};
        for (int k0 = 0; k0 < 1024; k0 += 64) {
#pragma unroll
            for (int c = tid; c < 1536; c += 256) {
                int row = c >> 3, cc = (c & 7) ^ (row & 7);
                if (row < 128)
                    gl_lds16(xb + (m0 + row) * 1024 + k0 + cc * 8, As + c * 8);
                else
                    gl_lds16(wqt + (n0 + row - 128) * 1024 + k0 + cc * 8, Bs + (c - 1024) * 8);
            }
            __syncthreads();
#pragma unroll
            for (int kk = 0; kk < 2; ++kk) {
                bf16x8 af[4], bfr[2];
#pragma unroll
                for (int i = 0; i < 4; ++i)
                    af[i] = *swz(As, wm + i * 16 + l16, kk * 4 + quad);
#pragma unroll
                for (int j = 0; j < 2; ++j)
                    bfr[j] = *swz(Bs, wn + j * 16 + l16, kk * 4 + quad);
#pragma unroll
                for (int i = 0; i < 4; ++i)
#pragma unroll
                    for (int j = 0; j < 2; ++j)
                        acc[i][j] = __builtin_amdgcn_mfma_f32_16x16x32_bf16(af[i], bfr[j], acc[i][j], 0, 0, 0);
            }
            __syncthreads();
        }
#pragma unroll
        for (int i = 0; i < 4; ++i) {
            long row = m0 + wm + i * 16 + quad * 4;
#pragma unroll
            for (int j = 0; j < 2; ++j) {
                int col = (int)n0 + wn + j * 16 + l16;
                float bb = cab[col];
#pragma unroll
                for (int r = 0; r < 4; ++r)
                    tb[(row + r) * 1024 + col] = (__bf16)(acc[i][j][r] + bb);
            }
        }
    } else {
        // ---- v-tile: 128x128, transpose out ----
        __bf16* As = smem;
        __bf16* Bs = smem + 8192;
        const int v2 = bid - 512;
        const int bx = v2 & 7, by = v2 >> 3;
        const long m0 = (long)by * 128;
        const long n0 = (long)bx * 128;       // local d-range
        const int wm = (wave >> 1) * 64, wn = (wave & 1) * 64;

        f32x4 acc[4][4] = {};
        for (int k0 = 0; k0 < 1024; k0 += 64) {
#pragma unroll
            for (int c = tid; c < 2048; c += 256) {
                int row = c >> 3, cc = (c & 7) ^ (row & 7);
                if (row < 128)
                    gl_lds16(xb + (m0 + row) * 1024 + k0 + cc * 8, As + c * 8);
                else
                    gl_lds16(wvt + (n0 + row - 128) * 1024 + k0 + cc * 8, Bs + (c - 1024) * 8);
            }
            __syncthreads();
#pragma unroll
            for (int kk = 0; kk < 2; ++kk) {
                bf16x8 af[4], bfr[4];
#pragma unroll
                for (int i = 0; i < 4; ++i)
                    af[i] = *swz(As, wm + i * 16 + l16, kk * 4 + quad);
#pragma unroll
                for (int j = 0; j < 4; ++j)
                    bfr[j] = *swz(Bs, wn + j * 16 + l16, kk * 4 + quad);
#pragma unroll
                for (int i = 0; i < 4; ++i)
#pragma unroll
                    for (int j = 0; j < 4; ++j)
                        acc[i][j] = __builtin_amdgcn_mfma_f32_16x16x32_bf16(af[i], bfr[j], acc[i][j], 0, 0, 0);
            }
            __syncthreads();
        }
        __syncthreads();
#pragma unroll
        for (int i = 0; i < 4; ++i) {
#pragma unroll
            for (int j = 0; j < 4; ++j) {
                int col = (int)n0 + wn + j * 16 + l16;     // global d 0..1023
                float bb = cab[2048 + col];
                bf16x4 v;
#pragma unroll
                for (int r = 0; r < 4; ++r) v[r] = (__bf16)(acc[i][j][r] + bb);
                *(bf16x4*)(smem + (wn + j * 16 + l16) * 136 + wm + i * 16 + quad * 4) = v;
            }
        }
        __syncthreads();
        const int bb2 = (int)(m0 >> 11);
        const int sl = (int)(m0 & 2047);
#pragma unroll
        for (int pass = 0; pass < 16; ++pass) {
            int idx = pass * 256 + tid;
            int n = idx >> 5;             // 0..127
            int mc = (idx & 31) * 4;      // 0..124
            bf16x4 v = *(const bf16x4*)(smem + n * 136 + mc);
            *(bf16x4*)(vt + ((long)(bb2 * 1024 + (int)n0 + n)) * 2048 + sl + mc) = v;
        }
    }
}

// ---------------------------------------------------------------------------
// Flash attention + fused q mini-GEMM, pair-balanced, wave-group specialized.
// grid (32, 16) x 512 threads: x = bh, y = pair.
// Prologue: q[qt][h*64..+64] = (t Wk^T + kb)*QSCALE computed per block —
//   the 512 blocks partition q exactly (rows by (b,pair), cols by h), so
//   this is the whole q-GEMM with zero duplication and no qbuf round-trip.
// Main loop: identical to the proven r6 structure (43 us).
// ---------------------------------------------------------------------------
__global__ __launch_bounds__(512) void attn_kernel(
    const __bf16* __restrict__ T,   // t = x Wq + qb  [4096][1024]
    const __bf16* __restrict__ Xb,  // [4096][1024]
    const __bf16* __restrict__ VT,  // [2048][2048]
    const __bf16* __restrict__ WK,  // wkn [1024][1024]
    const float* __restrict__ cab,  // biases (kb at +1024)
    __bf16* __restrict__ O)         // [4096][1024]
{
    __shared__ __bf16 Ks[2 * 8192];
    __shared__ __bf16 Vs[2 * 8192];
    __shared__ __bf16 Ps[8 * 1024];
    const int tid = threadIdx.x;
    const int lane = tid & 63;
    const int wave = tid >> 6;        // 0..7
    const int group = wave >> 2;      // 0 -> qa, 1 -> qb
    const int w4 = wave & 3;
    const int quad = lane >> 4, l16 = lane & 15;
    const int qa = blockIdx.y;        // 0..15
    const int qb = 31 - qa;           // 16..31
    const int qt = group ? qb : qa;
    const int bh = blockIdx.x;
    const int b = bh >> 4, h = bh & 15;
    const long rowbase = (long)b * 2048;

    const int s0 = tid;               // 0..511, row = s0>>3 in [0,64)
    const int c0 = ((s0 & 7) ^ ((s0 >> 3) & 7)) * 8;

    bf16x8 ones;
#pragma unroll
    for (int i = 0; i < 8; ++i) ones[i] = (__bf16)1.0f;

    // ---- q mini-GEMM: q_tile[qr][d] = (t Wk^T + kb)*QSCALE into Ps ----
    bf16x8 qfr[2];
    {
        f32x4 qacc[4] = {};
        for (int k0 = 0; k0 < 1024; k0 += 64) {
#pragma unroll
            for (int u = 0; u < 3; ++u) {
                int c = tid + u * 512;            // 0..1535
                if (c < 1024) {                   // t rows: qa tile then qb tile
                    int lr = c >> 3;              // 0..127
                    int cc = (c & 7) ^ (lr & 7);
                    int grow = (lr < 64) ? qa * 64 + lr : qb * 64 + (lr - 64);
                    gl_lds16(T + (rowbase + grow) * 1024 + k0 + cc * 8, Ks + c * 8);
                } else {                          // Wk rows h*64..+64
                    int w = c - 1024;
                    int lr = w >> 3;              // 0..63
                    int cc = (w & 7) ^ (lr & 7);
                    gl_lds16(WK + (long)(h * 64 + lr) * 1024 + k0 + cc * 8, Vs + w * 8);
                }
            }
            __syncthreads();
#pragma unroll
            for (int kk = 0; kk < 2; ++kk) {
                bf16x8 af = *swz(Ks + group * 4096, w4 * 16 + l16, kk * 4 + quad);
#pragma unroll
                for (int dt = 0; dt < 4; ++dt) {
                    bf16x8 bfr = *swz(Vs, dt * 16 + l16, kk * 4 + quad);
                    qacc[dt] = __builtin_amdgcn_mfma_f32_16x16x32_bf16(af, bfr, qacc[dt], 0, 0, 0);
                }
            }
            __syncthreads();
        }
        // epilogue: +kb, *QSCALE, write swizzled [128 rows][64 d] into Ps
#pragma unroll
        for (int dt = 0; dt < 4; ++dt) {
            int d = dt * 16 + l16;
            float bb = cab[1024 + h * 64 + d];
#pragma unroll
            for (int r = 0; r < 4; ++r) {
                int row = group * 64 + w4 * 16 + quad * 4 + r;
                float v = (qacc[dt][r] + bb) * QSCALE;
                *(__bf16*)((char*)Ps + row * 128 + (((d >> 3) ^ (row & 7)) * 16) + (d & 7) * 2) = (__bf16)v;
            }
        }
        __syncthreads();
        // reload as B-operand frags (same pattern as the old global q load)
        qfr[0] = *swz(Ps + group * 4096, w4 * 16 + l16, quad);
        qfr[1] = *swz(Ps + group * 4096, w4 * 16 + l16, 4 + quad);
    }

    const __bf16* kp0 = Xb + (rowbase + (s0 >> 3)) * 1024 + h * 64 + c0;
    const __bf16* vp0 = VT + ((long)(b * 1024 + h * 64 + (s0 >> 3))) * 2048 + c0;

    auto stage_tile = [&](int j, int buf, int sub) {
        gl_lds16(kp0 + (long)j * 65536, Ks + buf * 8192 + sub * 4096 + s0 * 8);
        gl_lds16(vp0 + j * 64, Vs + buf * 8192 + sub * 4096 + s0 * 8);
    };
    stage_tile(0, 0, 0);
    stage_tile(1, 0, 1);

    const int nouter = (qb + 2) >> 1;     // ceil((qb+1)/2)

    f32x4 oacc[4] = {};
    f32x4 lacc = {};
    __bf16* Pw = Ps + wave * 1024;

    for (int jj = 0; jj < nouter; ++jj) {
        __syncthreads();                  // buf ready; qfr loads + prev reads done
        if (jj + 1 < nouter) {
            stage_tile(2 * jj + 2, (jj + 1) & 1, 0);
            stage_tile(2 * jj + 3, (jj + 1) & 1, 1);
        }

#pragma unroll
        for (int sub = 0; sub < 2; ++sub) {
            const int j = 2 * jj + sub;
            if (j > qt) continue;         // wave-uniform
            const __bf16* Kb = Ks + (jj & 1) * 8192 + sub * 4096;
            const __bf16* Vb = Vs + (jj & 1) * 8192 + sub * 4096;

            bf16x8 kf[2][4], vf[2][4];
#pragma unroll
            for (int kk = 0; kk < 2; ++kk)
#pragma unroll
                for (int kt = 0; kt < 4; ++kt) {
                    kf[kk][kt] = *swz(Kb, kt * 16 + l16, kk * 4 + quad);
                    vf[kk][kt] = *swz(Vb, kt * 16 + l16, kk * 4 + quad);
                }

            // S^T = K Q^T : rows = kv, cols = q (this wave's 16-q strip)
            f32x4 sacc[4] = {};
            __builtin_amdgcn_s_setprio(1);
#pragma unroll
            for (int kk = 0; kk < 2; ++kk)
#pragma unroll
                for (int kt = 0; kt < 4; ++kt)
                    sacc[kt] = __builtin_amdgcn_mfma_f32_16x16x32_bf16(
                        kf[kk][kt], qfr[kk], sacc[kt], 0, 0, 0);
            __builtin_amdgcn_s_setprio(0);

            // p = exp2(s); masking branch only on the diagonal tile
            if (j == qt) {
                const int qloc = w4 * 16 + l16;
#pragma unroll
                for (int kt = 0; kt < 4; ++kt) {
                    bf16x4 pk;
#pragma unroll
                    for (int r = 0; r < 4; ++r) {
                        float s = sacc[kt][r];
                        if (kt * 16 + quad * 4 + r > qloc) s = -1e30f;
                        pk[r] = (__bf16)exp2f(s);
                    }
                    *(bf16x4*)((char*)Pw + l16 * 128 +
                               (((kt * 2 + (quad >> 1)) ^ (l16 & 7)) * 16) + (quad & 1) * 8) = pk;
                }
            } else {
#pragma unroll
                for (int kt = 0; kt < 4; ++kt) {
                    bf16x4 pk;
#pragma unroll
                    for (int r = 0; r < 4; ++r)
                        pk[r] = (__bf16)exp2f(sacc[kt][r]);
                    *(bf16x4*)((char*)Pw + l16 * 128 +
                               (((kt * 2 + (quad >> 1)) ^ (l16 & 7)) * 16) + (quad & 1) * 8) = pk;
                }
            }

            // O^T += VT * P^T ; l += ones * P^T   (per-wave P buffer)
            __builtin_amdgcn_s_setprio(1);
#pragma unroll
            for (int kk = 0; kk < 2; ++kk) {
                bf16x8 pf = *swz(Pw, l16, kk * 4 + quad);
                lacc = __builtin_amdgcn_mfma_f32_16x16x32_bf16(ones, pf, lacc, 0, 0, 0);
#pragma unroll
                for (int dt = 0; dt < 4; ++dt)
                    oacc[dt] = __builtin_amdgcn_mfma_f32_16x16x32_bf16(
                        vf[kk][dt], pf, oacc[dt], 0, 0, 0);
            }
            __builtin_amdgcn_s_setprio(0);
        }
    }

    // epilogue: normalize (l complete in every lane) and store
    {
        float inv = 1.0f / lacc[0];
        long row = rowbase + qt * 64 + w4 * 16 + l16;
#pragma unroll
        for (int dt = 0; dt < 4; ++dt) {
            bf16x4 ov;
#pragma unroll
            for (int r = 0; r < 4; ++r) ov[r] = (__bf16)(oacc[dt][r] * inv);
            *(bf16x4*)(O + row * 1024 + h * 64 + dt * 16 + quad * 4) = ov;
        }
    }
}

// ---------------------------------------------------------------------------
// proj GEMM: C[M,*] = (A[M,K] x BT[N,K] + bias).  BK = 64, BN = 64.
// ---------------------------------------------------------------------------
__global__ __launch_bounds__(256) void gemm_proj(
    const __bf16* __restrict__ A, const __bf16* __restrict__ B,
    const float* __restrict__ bias, float* __restrict__ C)
{
    __shared__ __bf16 As[128 * 64];
    __shared__ __bf16 Bs[64 * 64];
    const int tid = threadIdx.x;
    const int lane = tid & 63;
    const int wave = tid >> 6;
    const int quad = lane >> 4, l16 = lane & 15;
    const long m0 = (long)blockIdx.y * 128;
    const long n0 = (long)blockIdx.x * 64;
    const int wm = (wave >> 1) * 64, wn = (wave & 1) * 32;

    f32x4 acc[4][2] = {};

    for (int k0 = 0; k0 < 1024; k0 += 64) {
#pragma unroll
        for (int c = tid; c < 1536; c += 256) {
            int row = c >> 3, cc = (c & 7) ^ (row & 7);
            if (row < 128)
                gl_lds16(A + (m0 + row) * 1024 + k0 + cc * 8, As + c * 8);
            else
                gl_lds16(B + (n0 + row - 128) * 1024 + k0 + cc * 8, Bs + (c - 1024) * 8);
        }
        __syncthreads();
#pragma unroll
        for (int kk = 0; kk < 2; ++kk) {
            bf16x8 af[4], bfr[2];
#pragma unroll
            for (int i = 0; i < 4; ++i)
                af[i] = *swz(As, wm + i * 16 + l16, kk * 4 + quad);
#pragma unroll
            for (int j = 0; j < 2; ++j)
                bfr[j] = *swz(Bs, wn + j * 16 + l16, kk * 4 + quad);
#pragma unroll
            for (int i = 0; i < 4; ++i)
#pragma unroll
                for (int j = 0; j < 2; ++j)
                    acc[i][j] = __builtin_amdgcn_mfma_f32_16x16x32_bf16(af[i], bfr[j], acc[i][j], 0, 0, 0);
        }
        __syncthreads();
    }
#pragma unroll
    for (int i = 0; i < 4; ++i) {
        long row = m0 + wm + i * 16 + quad * 4;
#pragma unroll
        for (int j = 0; j < 2; ++j) {
            int col = (int)n0 + wn + j * 16 + l16;
            float bb = bias[col];
#pragma unroll
            for (int r = 0; r < 4; ++r)
                C[(row + r) * 1024 + col] = acc[i][j][r] + bb;
        }
    }
}

// ---------------------------------------------------------------------------
extern "C" void kernel_launch(void* const* d_in, const int* in_sizes, int n_in,
                              void* d_out, int out_size, void* d_ws, size_t ws_size,
                              hipStream_t stream) {
    const float* x   = (const float*)d_in[0];
    const float* caw = (const float*)d_in[1];
    const float* cab = (const float*)d_in[2];
    const float* cpw = (const float*)d_in[3];
    const float* cpb = (const float*)d_in[4];

    char* p = (char*)d_ws;
    auto alloc = [&](size_t bytes) {
        void* r = (void*)p;
        p += (bytes + 255) & ~(size_t)255;
        return r;
    };
    __bf16* xb    = (__bf16*)alloc(4096UL * 1024 * 2);   // x bf16
    __bf16* wkn   = (__bf16*)alloc(1024UL * 1024 * 2);   // Wk rows
    __bf16* wvt   = (__bf16*)alloc(1024UL * 1024 * 2);   // Wv^T
    __bf16* wqt   = (__bf16*)alloc(1024UL * 1024 * 2);   // Wq^T
    __bf16* wpt   = (__bf16*)alloc(1024UL * 1024 * 2);   // Wp^T
    __bf16* tb    = (__bf16*)alloc(4096UL * 1024 * 2);   // t = x Wq + qb
    __bf16* abuf  = (__bf16*)alloc(4096UL * 1024 * 2);   // attn out
    __bf16* vt    = (__bf16*)alloc(2048UL * 2048 * 2);   // V^T per (b,h)

    // pure-BW prep: converts + transposes
    prep_kernel<<<8192, 256, 0, stream>>>(x, caw, cpw, xb, wvt, wpt, wqt, wkn);
    // t = x Wq + qb  AND  V^T (independent; one launch, 3 blocks/CU)
    gemm_tv<<<768, 256, 0, stream>>>(xb, wqt, wvt, cab, tb, vt);
    // attention with fused q mini-GEMM (q never materialized globally)
    attn_kernel<<<dim3(32, 16), 512, 0, stream>>>(tb, xb, vt, wkn, cab, abuf);
    // out = attn @ Wp + pb (fp32)
    gemm_proj<<<dim3(16, 32), 256, 0, stream>>>(abuf, wpt, cpb, (float*)d_out);
    (void)in_sizes; (void)n_in; (void)out_size; (void)ws_size;
}